// Round 2
// baseline (966.564 us; speedup 1.0000x reference)
//
#include <hip/hip_runtime.h>

#define NN 50000
#define DD 128
#define HH 8
#define EE 1600000
#define LL 2

typedef unsigned short u16;
typedef __attribute__((ext_vector_type(8))) __bf16 bf16x8;
typedef __attribute__((ext_vector_type(4))) float f32x4;

__device__ __forceinline__ float bf2f(u16 u){
    return __uint_as_float(((unsigned int)u) << 16);
}
__device__ __forceinline__ u16 f2bf(float f){
    unsigned int x = __float_as_uint(f);
    x = x + 0x7fff + ((x >> 16) & 1);   // round-to-nearest-even
    return (u16)(x >> 16);
}

// ---------------- fp32 -> bf16 bulk convert ----------------
__global__ __launch_bounds__(256) void f2b4_kernel(const float* __restrict__ in, u16* __restrict__ out, int n4){
    int i = blockIdx.x * 256 + threadIdx.x;
    if (i < n4){
        float4 v = ((const float4*)in)[i];
        ushort4 o;
        o.x = f2bf(v.x); o.y = f2bf(v.y); o.z = f2bf(v.z); o.w = f2bf(v.w);
        ((ushort4*)out)[i] = o;
    }
}

// ---------------- CSR build ----------------
__global__ __launch_bounds__(256) void count_kernel(const int* __restrict__ dst, int* __restrict__ cnt){
    int e = blockIdx.x * 256 + threadIdx.x;
    if (e < EE) atomicAdd(&cnt[dst[e]], 1);
}

__global__ __launch_bounds__(1024) void scan_kernel(const int* __restrict__ cnt,
                                                    int* __restrict__ offs, int* __restrict__ cur){
    __shared__ int wsum[16];
    __shared__ int carry_s;
    __shared__ int ctot_s;
    int t = threadIdx.x, lane = t & 63, w = t >> 6;
    if (t == 0){ offs[0] = 0; cur[0] = 0; carry_s = 0; }
    __syncthreads();
    for (int base = 0; base < NN; base += 1024){
        int i = base + t;
        int x = (i < NN) ? cnt[i] : 0;
        int v = x;
        #pragma unroll
        for (int d = 1; d < 64; d <<= 1){ int u = __shfl_up(v, d); if (lane >= d) v += u; }
        if (lane == 63) wsum[w] = v;
        __syncthreads();
        if (t < 16){
            int sv = wsum[t];
            int iv = sv;
            #pragma unroll
            for (int d = 1; d < 16; d <<= 1){ int u = __shfl_up(iv, d); if (t >= d) iv += u; }
            wsum[t] = iv - sv;            // exclusive prefix of wave sums
            if (t == 15) ctot_s = iv;     // chunk total
        }
        __syncthreads();
        int incl = carry_s + wsum[w] + v;
        if (i < NN){ offs[i + 1] = incl; cur[i + 1] = incl; }
        __syncthreads();
        if (t == 0) carry_s += ctot_s;
        __syncthreads();
    }
}

__global__ __launch_bounds__(256) void fill_kernel(const int* __restrict__ dst,
                                                   int* __restrict__ cur, int* __restrict__ eid){
    int e = blockIdx.x * 256 + threadIdx.x;
    if (e < EE){
        int p = atomicAdd(&cur[dst[e]], 1);
        eid[p] = e;
    }
}

// ---------------- weight prep (fp32 in -> bf16 transposed out) ----------------
__global__ __launch_bounds__(256) void qkvpack_kernel(const float* __restrict__ Wq, const float* __restrict__ Wk,
                                                      const float* __restrict__ Wv, const float* __restrict__ bq,
                                                      const float* __restrict__ bk, const float* __restrict__ bv,
                                                      u16* __restrict__ Wt, float* __restrict__ bcat){
    int l = blockIdx.y;
    int idx = blockIdx.x * 256 + threadIdx.x;   // over 384*128
    if (idx < 384 * 128){
        int n = idx >> 7, k = idx & 127;
        const float* W = (n < 128) ? Wq : (n < 256) ? Wk : Wv;
        int nc = n & 127;
        Wt[(size_t)l * 384 * 128 + idx] = f2bf(W[(size_t)l * 128 * 128 + k * 128 + nc]);
        if (k == 0){
            const float* bb = (n < 128) ? bq : (n < 256) ? bv : bv;
            bb = (n < 128) ? bq : (n < 256) ? bk : bv;
            bcat[l * 384 + n] = bb[l * 128 + nc];
        }
    }
}

// generic transpose+convert: in fp32 [R][C] -> out bf16 [C][R], per-layer via blockIdx.y
__global__ __launch_bounds__(256) void transpose_kernel(const float* __restrict__ in, u16* __restrict__ out,
                                                        int R, int C){
    size_t mat = (size_t)blockIdx.y * R * C;
    int idx = blockIdx.x * 256 + threadIdx.x;
    if (idx < R * C){
        int r = idx / C, c = idx % C;
        out[mat + (size_t)c * R + r] = f2bf(in[mat + idx]);
    }
}

// ---------------- GEMM: out[M][N] = A[M][K] @ W[K][N] (+bias, +resid, relu) ----------------
// A, Wt (=W^T [N][K]), resid, out are bf16; bias fp32; fp32 accumulate via MFMA 16x16x32.
#define BM 64
#define BN 64
#define BKK 64

__global__ __launch_bounds__(256) void gemm_bf16(const u16* __restrict__ A, const u16* __restrict__ Wt,
                                                 const float* __restrict__ bias, const u16* __restrict__ resid,
                                                 u16* __restrict__ out, int M, int K, int N, int relu){
    __shared__ u16 As[BM][BKK + 8];
    __shared__ u16 Bs[BN][BKK + 8];
    int tid = threadIdx.x;
    int m0 = blockIdx.x * BM, n0 = blockIdx.y * BN;
    int lane = tid & 63, w = tid >> 6;
    int wm = w >> 1, wn = w & 1;
    int l15 = lane & 15, lk = (lane >> 4) * 8;

    f32x4 acc[2][2];
    #pragma unroll
    for (int mi = 0; mi < 2; mi++)
        #pragma unroll
        for (int ni = 0; ni < 2; ni++)
            acc[mi][ni] = (f32x4){0.f, 0.f, 0.f, 0.f};

    int sr = tid >> 3;              // 0..31
    int sc = (tid & 7) * 8;         // 0..56

    for (int k0 = 0; k0 < K; k0 += BKK){
        __syncthreads();
        #pragma unroll
        for (int p = 0; p < 2; p++){
            int row = p * 32 + sr;
            int gm = m0 + row;
            uint4 va = make_uint4(0, 0, 0, 0);
            if (gm < M) va = *(const uint4*)(A + (size_t)gm * K + k0 + sc);
            *(uint4*)(&As[row][sc]) = va;
            uint4 vb = *(const uint4*)(Wt + (size_t)(n0 + row) * K + k0 + sc);
            *(uint4*)(&Bs[row][sc]) = vb;
        }
        __syncthreads();
        #pragma unroll
        for (int ks = 0; ks < 2; ks++){
            bf16x8 a[2], b[2];
            #pragma unroll
            for (int i = 0; i < 2; i++){
                a[i] = *(const bf16x8*)(&As[wm * 32 + i * 16 + l15][ks * 32 + lk]);
                b[i] = *(const bf16x8*)(&Bs[wn * 32 + i * 16 + l15][ks * 32 + lk]);
            }
            #pragma unroll
            for (int mi = 0; mi < 2; mi++)
                #pragma unroll
                for (int ni = 0; ni < 2; ni++)
                    acc[mi][ni] = __builtin_amdgcn_mfma_f32_16x16x32_bf16(a[mi], b[ni], acc[mi][ni], 0, 0, 0);
        }
    }

    #pragma unroll
    for (int mi = 0; mi < 2; mi++)
        #pragma unroll
        for (int ni = 0; ni < 2; ni++){
            int col = n0 + wn * 32 + ni * 16 + l15;
            float bval = bias[col];
            #pragma unroll
            for (int j = 0; j < 4; j++){
                int row = m0 + wm * 32 + mi * 16 + (lane >> 4) * 4 + j;
                if (row < M){
                    float v = acc[mi][ni][j] + bval;
                    if (resid) v += bf2f(resid[(size_t)row * N + col]);
                    if (relu) v = fmaxf(v, 0.f);
                    out[(size_t)row * N + col] = f2bf(v);
                }
            }
        }
}

// ---------------- edge attention aggregation ----------------
// QKV: [N][384] bf16 (Q|K|V). One wave per dst node; lane owns dims 2l,2l+1 (head = l>>3).
__global__ __launch_bounds__(256) void edge_attn_kernel(const u16* __restrict__ QKV,
                                                        const int* __restrict__ src,
                                                        const int* __restrict__ offs,
                                                        const int* __restrict__ eid,
                                                        u16* __restrict__ att){
    int n = blockIdx.x * 4 + (threadIdx.x >> 6);
    if (n >= NN) return;
    int lane = threadIdx.x & 63;

    unsigned int q2 = *(const unsigned int*)(QKV + (size_t)n * 384 + 2 * lane);
    float qa = bf2f((u16)(q2 & 0xffff)), qb = bf2f((u16)(q2 >> 16));

    float wa = 0.f, wb = 0.f, z = 0.f;
    int e0 = offs[n], e1 = offs[n + 1];
    for (int i = e0; i < e1; i++){
        int e = eid[i];
        int s = src[e];
        const u16* base = QKV + (size_t)s * 384;
        unsigned int k2 = *(const unsigned int*)(base + 128 + 2 * lane);
        unsigned int v2 = *(const unsigned int*)(base + 256 + 2 * lane);
        float p = qa * bf2f((u16)(k2 & 0xffff)) + qb * bf2f((u16)(k2 >> 16));
        p += __shfl_xor(p, 1);
        p += __shfl_xor(p, 2);
        p += __shfl_xor(p, 4);
        p *= 0.25f;                                  // 1/sqrt(16)
        p = fminf(fmaxf(p, -5.f), 5.f);
        float sc = __expf(p);
        wa += sc * bf2f((u16)(v2 & 0xffff));
        wb += sc * bf2f((u16)(v2 >> 16));
        z += sc;
    }
    float inv = 1.f / (z + 1e-6f);
    unsigned int o = (unsigned int)f2bf(wa * inv) | ((unsigned int)f2bf(wb * inv) << 16);
    *(unsigned int*)(att + (size_t)n * DD + 2 * lane) = o;
}

// ---------------- layernorm (x bf16 in; out bf16 or fp32) ----------------
__global__ __launch_bounds__(256) void ln_kernel(const u16* __restrict__ x, const float* __restrict__ g,
                                                 const float* __restrict__ b, u16* __restrict__ out_bf,
                                                 float* __restrict__ out_f){
    int row = blockIdx.x * 4 + (threadIdx.x >> 6);
    if (row >= NN) return;
    int lane = threadIdx.x & 63;
    unsigned int x2 = *(const unsigned int*)(x + (size_t)row * DD + 2 * lane);
    float xa = bf2f((u16)(x2 & 0xffff)), xb = bf2f((u16)(x2 >> 16));
    float s = xa + xb;
    #pragma unroll
    for (int d = 1; d < 64; d <<= 1) s += __shfl_xor(s, d);
    float mean = s * (1.f / 128.f);
    float da = xa - mean, db = xb - mean;
    float v = da * da + db * db;
    #pragma unroll
    for (int d = 1; d < 64; d <<= 1) v += __shfl_xor(v, d);
    float r = rsqrtf(v * (1.f / 128.f) + 1e-5f);
    float2 gv = *(const float2*)(g + 2 * lane);
    float2 bv = *(const float2*)(b + 2 * lane);
    float oa = da * r * gv.x + bv.x;
    float ob = db * r * gv.y + bv.y;
    if (out_f){
        *(float2*)(out_f + (size_t)row * DD + 2 * lane) = make_float2(oa, ob);
    } else {
        unsigned int o = (unsigned int)f2bf(oa) | ((unsigned int)f2bf(ob) << 16);
        *(unsigned int*)(out_bf + (size_t)row * DD + 2 * lane) = o;
    }
}

// ---------------- host orchestration ----------------
extern "C" void kernel_launch(void* const* d_in, const int* in_sizes, int n_in,
                              void* d_out, int out_size, void* d_ws, size_t ws_size,
                              hipStream_t stream){
    const float* h_in = (const float*)d_in[0];
    const int* src  = (const int*)d_in[1];
    const int* dst  = (const int*)d_in[2];
    const float* Wq = (const float*)d_in[3];
    const float* bq = (const float*)d_in[4];
    const float* Wk = (const float*)d_in[5];
    const float* bk = (const float*)d_in[6];
    const float* Wv = (const float*)d_in[7];
    const float* bv = (const float*)d_in[8];
    const float* Wo = (const float*)d_in[9];
    const float* bo = (const float*)d_in[10];
    const float* W1 = (const float*)d_in[11];
    const float* b1 = (const float*)d_in[12];
    const float* W2 = (const float*)d_in[13];
    const float* b2 = (const float*)d_in[14];
    const float* ln1_g = (const float*)d_in[15];
    const float* ln1_b = (const float*)d_in[16];
    const float* ln2_g = (const float*)d_in[17];
    const float* ln2_b = (const float*)d_in[18];
    float* outp = (float*)d_out;

    char* ws = (char*)d_ws;
    auto alloc = [&](size_t bytes) -> char* {
        char* p = ws;
        ws += (bytes + 255) & ~(size_t)255;
        return p;
    };
    int* cnt   = (int*)alloc((size_t)NN * 4);
    int* offs  = (int*)alloc((size_t)(NN + 1) * 4);
    int* cur   = (int*)alloc((size_t)(NN + 1) * 4);
    int* eid   = (int*)alloc((size_t)EE * 4);
    u16* WtQKV = (u16*)alloc((size_t)LL * 384 * 128 * 2);
    float* bQKV = (float*)alloc((size_t)LL * 384 * 4);
    u16* WtO   = (u16*)alloc((size_t)LL * 128 * 128 * 2);
    u16* WtF1  = (u16*)alloc((size_t)LL * 256 * 128 * 2);
    u16* WtF2  = (u16*)alloc((size_t)LL * 128 * 256 * 2);
    u16* hb    = (u16*)alloc((size_t)NN * DD * 2);
    u16* QKV   = (u16*)alloc((size_t)NN * 384 * 2);   // also reused as FFN mid (N*256)
    u16* att   = (u16*)alloc((size_t)NN * DD * 2);
    u16* rbuf  = (u16*)alloc((size_t)NN * DD * 2);
    u16* h1    = (u16*)alloc((size_t)NN * DD * 2);
    u16* hmid  = (u16*)alloc((size_t)NN * DD * 2);

    // CSR build (edges identical for both layers)
    hipMemsetAsync(cnt, 0, (size_t)NN * 4, stream);
    count_kernel<<<EE / 256, 256, 0, stream>>>(dst, cnt);
    scan_kernel<<<1, 1024, 0, stream>>>(cnt, offs, cur);
    fill_kernel<<<EE / 256, 256, 0, stream>>>(dst, cur, eid);

    // input + weight prep
    f2b4_kernel<<<(NN * DD / 4 + 255) / 256, 256, 0, stream>>>(h_in, hb, NN * DD / 4);
    qkvpack_kernel<<<dim3(192, LL), 256, 0, stream>>>(Wq, Wk, Wv, bq, bk, bv, WtQKV, bQKV);
    transpose_kernel<<<dim3(64, LL), 256, 0, stream>>>(Wo, WtO, 128, 128);
    transpose_kernel<<<dim3(128, LL), 256, 0, stream>>>(W1, WtF1, 128, 256);
    transpose_kernel<<<dim3(128, LL), 256, 0, stream>>>(W2, WtF2, 256, 128);

    const int MB = (NN + BM - 1) / BM;   // 782
    const u16* hcur = hb;
    for (int l = 0; l < LL; l++){
        // QKV projection (N=384)
        gemm_bf16<<<dim3(MB, 6), 256, 0, stream>>>(hcur, WtQKV + (size_t)l * 384 * 128,
                                                   bQKV + l * 384, nullptr, QKV, NN, 128, 384, 0);
        // edge attention
        edge_attn_kernel<<<NN / 4, 256, 0, stream>>>(QKV, src, offs, eid, att);
        // output projection + residual
        gemm_bf16<<<dim3(MB, 2), 256, 0, stream>>>(att, WtO + (size_t)l * 128 * 128,
                                                   bo + l * 128, hcur, rbuf, NN, 128, 128, 0);
        ln_kernel<<<NN / 4, 256, 0, stream>>>(rbuf, ln1_g + l * 128, ln1_b + l * 128, h1, nullptr);
        // FFN
        gemm_bf16<<<dim3(MB, 4), 256, 0, stream>>>(h1, WtF1 + (size_t)l * 256 * 128,
                                                   b1 + l * 256, nullptr, QKV, NN, 128, 256, 1);
        gemm_bf16<<<dim3(MB, 2), 256, 0, stream>>>(QKV, WtF2 + (size_t)l * 128 * 256,
                                                   b2 + l * 128, h1, rbuf, NN, 256, 128, 0);
        // final LN of last layer -> fp32 d_out; else bf16 hmid
        if (l == LL - 1)
            ln_kernel<<<NN / 4, 256, 0, stream>>>(rbuf, ln2_g + l * 128, ln2_b + l * 128, nullptr, outp);
        else
            ln_kernel<<<NN / 4, 256, 0, stream>>>(rbuf, ln2_g + l * 128, ln2_b + l * 128, hmid, nullptr);
        hcur = hmid;
    }
}

// Round 3
// 657.955 us; speedup vs baseline: 1.4690x; 1.4690x over previous
//
#include <hip/hip_runtime.h>

#define NN 50000
#define DD 128
#define HH 8
#define EE 1600000
#define LL 2

typedef unsigned short u16;
typedef __attribute__((ext_vector_type(8))) __bf16 bf16x8;
typedef __attribute__((ext_vector_type(4))) float f32x4;

__device__ __forceinline__ float bf2f(u16 u){
    return __uint_as_float(((unsigned int)u) << 16);
}
__device__ __forceinline__ u16 f2bf(float f){
    unsigned int x = __float_as_uint(f);
    x = x + 0x7fff + ((x >> 16) & 1);   // round-to-nearest-even
    return (u16)(x >> 16);
}

// ---------------- fp32 -> bf16 bulk convert ----------------
__global__ __launch_bounds__(256) void f2b4_kernel(const float* __restrict__ in, u16* __restrict__ out, int n4){
    int i = blockIdx.x * 256 + threadIdx.x;
    if (i < n4){
        float4 v = ((const float4*)in)[i];
        ushort4 o;
        o.x = f2bf(v.x); o.y = f2bf(v.y); o.z = f2bf(v.z); o.w = f2bf(v.w);
        ((ushort4*)out)[i] = o;
    }
}

// ---------------- CSR build ----------------
__global__ __launch_bounds__(256) void count_kernel(const int* __restrict__ dst, int* __restrict__ cnt){
    int e = blockIdx.x * 256 + threadIdx.x;
    if (e < EE) atomicAdd(&cnt[dst[e]], 1);
}

__global__ __launch_bounds__(1024) void scan_kernel(const int* __restrict__ cnt,
                                                    int* __restrict__ offs, int* __restrict__ cur){
    __shared__ int wsum[16];
    __shared__ int carry_s;
    __shared__ int ctot_s;
    int t = threadIdx.x, lane = t & 63, w = t >> 6;
    if (t == 0){ offs[0] = 0; cur[0] = 0; carry_s = 0; }
    __syncthreads();
    for (int base = 0; base < NN; base += 1024){
        int i = base + t;
        int x = (i < NN) ? cnt[i] : 0;
        int v = x;
        #pragma unroll
        for (int d = 1; d < 64; d <<= 1){ int u = __shfl_up(v, d); if (lane >= d) v += u; }
        if (lane == 63) wsum[w] = v;
        __syncthreads();
        if (t < 16){
            int sv = wsum[t];
            int iv = sv;
            #pragma unroll
            for (int d = 1; d < 16; d <<= 1){ int u = __shfl_up(iv, d); if (t >= d) iv += u; }
            wsum[t] = iv - sv;            // exclusive prefix of wave sums
            if (t == 15) ctot_s = iv;     // chunk total
        }
        __syncthreads();
        int incl = carry_s + wsum[w] + v;
        if (i < NN){ offs[i + 1] = incl; cur[i + 1] = incl; }
        __syncthreads();
        if (t == 0) carry_s += ctot_s;
        __syncthreads();
    }
}

// pre-gather src values into CSR order: removes one indirection in edge_attn
__global__ __launch_bounds__(256) void fill_kernel(const int* __restrict__ src, const int* __restrict__ dst,
                                                   int* __restrict__ cur, int* __restrict__ srcs){
    int e = blockIdx.x * 256 + threadIdx.x;
    if (e < EE){
        int p = atomicAdd(&cur[dst[e]], 1);
        srcs[p] = src[e];
    }
}

// ---------------- weight prep (fp32 in -> bf16 transposed out) ----------------
__global__ __launch_bounds__(256) void qkvpack_kernel(const float* __restrict__ Wq, const float* __restrict__ Wk,
                                                      const float* __restrict__ Wv, const float* __restrict__ bq,
                                                      const float* __restrict__ bk, const float* __restrict__ bv,
                                                      u16* __restrict__ Wt, float* __restrict__ bcat){
    int l = blockIdx.y;
    int idx = blockIdx.x * 256 + threadIdx.x;   // over 384*128
    if (idx < 384 * 128){
        int n = idx >> 7, k = idx & 127;
        const float* W = (n < 128) ? Wq : (n < 256) ? Wk : Wv;
        int nc = n & 127;
        Wt[(size_t)l * 384 * 128 + idx] = f2bf(W[(size_t)l * 128 * 128 + k * 128 + nc]);
        if (k == 0){
            const float* bb = (n < 128) ? bq : (n < 256) ? bk : bv;
            bcat[l * 384 + n] = bb[l * 128 + nc];
        }
    }
}

// generic transpose+convert: in fp32 [R][C] -> out bf16 [C][R], per-layer via blockIdx.y
__global__ __launch_bounds__(256) void transpose_kernel(const float* __restrict__ in, u16* __restrict__ out,
                                                        int R, int C){
    size_t mat = (size_t)blockIdx.y * R * C;
    int idx = blockIdx.x * 256 + threadIdx.x;
    if (idx < R * C){
        int r = idx / C, c = idx % C;
        out[mat + (size_t)c * R + r] = f2bf(in[mat + idx]);
    }
}

// ---------------- GEMM: out[M][N] = A[M][K] @ W[K][N] (+bias, relu) ----------------
#define BM 64
#define BN 64
#define BKK 64

__global__ __launch_bounds__(256) void gemm_bf16(const u16* __restrict__ A, const u16* __restrict__ Wt,
                                                 const float* __restrict__ bias,
                                                 u16* __restrict__ out, int M, int K, int N, int relu){
    __shared__ u16 As[BM][BKK + 8];
    __shared__ u16 Bs[BN][BKK + 8];
    int tid = threadIdx.x;
    int m0 = blockIdx.x * BM, n0 = blockIdx.y * BN;
    int lane = tid & 63, w = tid >> 6;
    int wm = w >> 1, wn = w & 1;
    int l15 = lane & 15, lk = (lane >> 4) * 8;

    f32x4 acc[2][2];
    #pragma unroll
    for (int mi = 0; mi < 2; mi++)
        #pragma unroll
        for (int ni = 0; ni < 2; ni++)
            acc[mi][ni] = (f32x4){0.f, 0.f, 0.f, 0.f};

    int sr = tid >> 3;              // 0..31
    int sc = (tid & 7) * 8;         // 0..56

    for (int k0 = 0; k0 < K; k0 += BKK){
        __syncthreads();
        #pragma unroll
        for (int p = 0; p < 2; p++){
            int row = p * 32 + sr;
            int gm = m0 + row;
            uint4 va = make_uint4(0, 0, 0, 0);
            if (gm < M) va = *(const uint4*)(A + (size_t)gm * K + k0 + sc);
            *(uint4*)(&As[row][sc]) = va;
            uint4 vb = *(const uint4*)(Wt + (size_t)(n0 + row) * K + k0 + sc);
            *(uint4*)(&Bs[row][sc]) = vb;
        }
        __syncthreads();
        #pragma unroll
        for (int ks = 0; ks < 2; ks++){
            bf16x8 a[2], b[2];
            #pragma unroll
            for (int i = 0; i < 2; i++){
                a[i] = *(const bf16x8*)(&As[wm * 32 + i * 16 + l15][ks * 32 + lk]);
                b[i] = *(const bf16x8*)(&Bs[wn * 32 + i * 16 + l15][ks * 32 + lk]);
            }
            #pragma unroll
            for (int mi = 0; mi < 2; mi++)
                #pragma unroll
                for (int ni = 0; ni < 2; ni++)
                    acc[mi][ni] = __builtin_amdgcn_mfma_f32_16x16x32_bf16(a[mi], b[ni], acc[mi][ni], 0, 0, 0);
        }
    }

    #pragma unroll
    for (int mi = 0; mi < 2; mi++)
        #pragma unroll
        for (int ni = 0; ni < 2; ni++){
            int col = n0 + wn * 32 + ni * 16 + l15;
            float bval = bias[col];
            #pragma unroll
            for (int j = 0; j < 4; j++){
                int row = m0 + wm * 32 + mi * 16 + (lane >> 4) * 4 + j;
                if (row < M){
                    float v = acc[mi][ni][j] + bval;
                    if (relu) v = fmaxf(v, 0.f);
                    out[(size_t)row * N + col] = f2bf(v);
                }
            }
        }
}

// ---------------- GEMM (N=128) + bias + residual + LayerNorm fused ----------------
// 4 waves as 2(m) x 2(n); wave tile 32x64. LDS A/B staging reused as fp32 C tile.
__global__ __launch_bounds__(256) void gemm_ln(const u16* __restrict__ A, const u16* __restrict__ Wt,
                                               const float* __restrict__ bias, const u16* __restrict__ resid,
                                               const float* __restrict__ g, const float* __restrict__ b,
                                               u16* __restrict__ out_bf, float* __restrict__ out_f,
                                               int M, int K){
    __shared__ __align__(16) char smem[64 * 132 * 4];   // 33792 B
    u16* As = (u16*)smem;              // [64][72]
    u16* Bs = As + 64 * 72;            // [128][72]
    float* Cs = (float*)smem;          // [64][132]

    int tid = threadIdx.x;
    int m0 = blockIdx.x * 64;
    int lane = tid & 63, w = tid >> 6;
    int wm = w >> 1, wn = w & 1;
    int l15 = lane & 15, lk = (lane >> 4) * 8;

    f32x4 acc[2][4];
    #pragma unroll
    for (int mi = 0; mi < 2; mi++)
        #pragma unroll
        for (int ni = 0; ni < 4; ni++)
            acc[mi][ni] = (f32x4){0.f, 0.f, 0.f, 0.f};

    int sr = tid >> 3;              // 0..31
    int sc = (tid & 7) * 8;         // 0..56

    for (int k0 = 0; k0 < K; k0 += BKK){
        __syncthreads();
        #pragma unroll
        for (int p = 0; p < 2; p++){
            int row = p * 32 + sr;
            int gm = m0 + row;
            uint4 va = make_uint4(0, 0, 0, 0);
            if (gm < M) va = *(const uint4*)(A + (size_t)gm * K + k0 + sc);
            *(uint4*)(&As[row * 72 + sc]) = va;
        }
        #pragma unroll
        for (int p = 0; p < 4; p++){
            int row = p * 32 + sr;
            uint4 vb = *(const uint4*)(Wt + (size_t)row * K + k0 + sc);
            *(uint4*)(&Bs[row * 72 + sc]) = vb;
        }
        __syncthreads();
        #pragma unroll
        for (int ks = 0; ks < 2; ks++){
            bf16x8 a[2], bb[4];
            #pragma unroll
            for (int i = 0; i < 2; i++)
                a[i] = *(const bf16x8*)(&As[(wm * 32 + i * 16 + l15) * 72 + ks * 32 + lk]);
            #pragma unroll
            for (int i = 0; i < 4; i++)
                bb[i] = *(const bf16x8*)(&Bs[(wn * 64 + i * 16 + l15) * 72 + ks * 32 + lk]);
            #pragma unroll
            for (int mi = 0; mi < 2; mi++)
                #pragma unroll
                for (int ni = 0; ni < 4; ni++)
                    acc[mi][ni] = __builtin_amdgcn_mfma_f32_16x16x32_bf16(a[mi], bb[ni], acc[mi][ni], 0, 0, 0);
        }
    }

    __syncthreads();   // all waves done reading As/Bs; reuse as Cs
    #pragma unroll
    for (int mi = 0; mi < 2; mi++)
        #pragma unroll
        for (int ni = 0; ni < 4; ni++){
            int col = wn * 64 + ni * 16 + l15;
            float bval = bias[col];
            #pragma unroll
            for (int j = 0; j < 4; j++){
                int row = wm * 32 + mi * 16 + (lane >> 4) * 4 + j;
                Cs[row * 132 + col] = acc[mi][ni][j] + bval;
            }
        }
    __syncthreads();

    float gva = g[lane], gvb = g[lane + 64];
    float bva = b[lane], bvb = b[lane + 64];
    for (int rr = 0; rr < 16; rr++){
        int row = w * 16 + rr;
        int gr = m0 + row;
        if (gr >= M) break;
        float xa = Cs[row * 132 + lane]      + bf2f(resid[(size_t)gr * 128 + lane]);
        float xb = Cs[row * 132 + 64 + lane] + bf2f(resid[(size_t)gr * 128 + 64 + lane]);
        float s = xa + xb;
        #pragma unroll
        for (int d = 1; d < 64; d <<= 1) s += __shfl_xor(s, d);
        float mean = s * (1.f / 128.f);
        float da = xa - mean, db = xb - mean;
        float v = da * da + db * db;
        #pragma unroll
        for (int d = 1; d < 64; d <<= 1) v += __shfl_xor(v, d);
        float r = rsqrtf(v * (1.f / 128.f) + 1e-5f);
        float oa = da * r * gva + bva;
        float ob = db * r * gvb + bvb;
        if (out_f){
            out_f[(size_t)gr * 128 + lane] = oa;
            out_f[(size_t)gr * 128 + 64 + lane] = ob;
        } else {
            out_bf[(size_t)gr * 128 + lane] = f2bf(oa);
            out_bf[(size_t)gr * 128 + 64 + lane] = f2bf(ob);
        }
    }
}

// ---------------- edge attention aggregation ----------------
// QKV: [N][384] bf16 (Q|K|V). One wave per dst node.
// K and V rows are contiguous (elements 128..383): one dwordx2 per lane fetches both.
// Lane l (<32): K dims 4l..4l+3, computes score for head l>>2. Lane l (>=32): V dims 4(l-32)..+3.
__global__ __launch_bounds__(256) void edge_attn_kernel(const u16* __restrict__ QKV,
                                                        const int* __restrict__ srcs,
                                                        const int* __restrict__ offs,
                                                        u16* __restrict__ att){
    int n = blockIdx.x * 4 + (threadIdx.x >> 6);
    if (n >= NN) return;
    int lane = threadIdx.x & 63;
    bool isV = lane >= 32;

    float q0, q1, q2, q3;
    {
        uint2 qv = *(const uint2*)(QKV + (size_t)n * 384 + 4 * (lane & 31));
        q0 = bf2f((u16)(qv.x & 0xffff)); q1 = bf2f((u16)(qv.x >> 16));
        q2 = bf2f((u16)(qv.y & 0xffff)); q3 = bf2f((u16)(qv.y >> 16));
    }
    const u16* kvbase = QKV + 128 + 4 * lane;

    float w0 = 0.f, w1 = 0.f, w2 = 0.f, w3 = 0.f, z = 0.f;

    auto proc = [&](uint2 kv){
        float a0 = bf2f((u16)(kv.x & 0xffff)), a1 = bf2f((u16)(kv.x >> 16));
        float a2 = bf2f((u16)(kv.y & 0xffff)), a3 = bf2f((u16)(kv.y >> 16));
        float p = q0 * a0 + q1 * a1 + q2 * a2 + q3 * a3;
        p += __shfl_xor(p, 1);
        p += __shfl_xor(p, 2);
        p *= 0.25f;                              // 1/sqrt(16)
        p = fminf(fmaxf(p, -5.f), 5.f);
        float sc = __expf(p);
        float scv = __shfl_xor(sc, 32);          // upper lanes receive their head's score
        float m = isV ? scv : 0.f;
        w0 += m * a0; w1 += m * a1; w2 += m * a2; w3 += m * a3;
        z += isV ? 0.f : sc;
    };

    int e0 = offs[n], e1 = offs[n + 1];
    int i = e0;
    for (; i + 3 < e1; i += 4){
        int s0 = srcs[i], s1 = srcs[i + 1], s2 = srcs[i + 2], s3 = srcs[i + 3];
        uint2 kv0 = *(const uint2*)(kvbase + (size_t)s0 * 384);
        uint2 kv1 = *(const uint2*)(kvbase + (size_t)s1 * 384);
        uint2 kv2 = *(const uint2*)(kvbase + (size_t)s2 * 384);
        uint2 kv3 = *(const uint2*)(kvbase + (size_t)s3 * 384);
        proc(kv0); proc(kv1); proc(kv2); proc(kv3);
    }
    for (; i < e1; i++){
        int s = srcs[i];
        uint2 kv = *(const uint2*)(kvbase + (size_t)s * 384);
        proc(kv);
    }

    float z2 = __shfl_xor(z, 32);                // upper lanes receive their head's z
    if (isV){
        float inv = 1.f / (z2 + 1e-6f);
        unsigned int oA = (unsigned int)f2bf(w0 * inv) | ((unsigned int)f2bf(w1 * inv) << 16);
        unsigned int oB = (unsigned int)f2bf(w2 * inv) | ((unsigned int)f2bf(w3 * inv) << 16);
        *(uint2*)(att + (size_t)n * DD + 4 * (lane - 32)) = make_uint2(oA, oB);
    }
}

// ---------------- host orchestration ----------------
extern "C" void kernel_launch(void* const* d_in, const int* in_sizes, int n_in,
                              void* d_out, int out_size, void* d_ws, size_t ws_size,
                              hipStream_t stream){
    const float* h_in = (const float*)d_in[0];
    const int* src  = (const int*)d_in[1];
    const int* dst  = (const int*)d_in[2];
    const float* Wq = (const float*)d_in[3];
    const float* bq = (const float*)d_in[4];
    const float* Wk = (const float*)d_in[5];
    const float* bk = (const float*)d_in[6];
    const float* Wv = (const float*)d_in[7];
    const float* bv = (const float*)d_in[8];
    const float* Wo = (const float*)d_in[9];
    const float* bo = (const float*)d_in[10];
    const float* W1 = (const float*)d_in[11];
    const float* b1 = (const float*)d_in[12];
    const float* W2 = (const float*)d_in[13];
    const float* b2 = (const float*)d_in[14];
    const float* ln1_g = (const float*)d_in[15];
    const float* ln1_b = (const float*)d_in[16];
    const float* ln2_g = (const float*)d_in[17];
    const float* ln2_b = (const float*)d_in[18];
    float* outp = (float*)d_out;

    char* ws = (char*)d_ws;
    auto alloc = [&](size_t bytes) -> char* {
        char* p = ws;
        ws += (bytes + 255) & ~(size_t)255;
        return p;
    };
    int* cnt   = (int*)alloc((size_t)NN * 4);
    int* offs  = (int*)alloc((size_t)(NN + 1) * 4);
    int* cur   = (int*)alloc((size_t)(NN + 1) * 4);
    int* srcs  = (int*)alloc((size_t)EE * 4);
    u16* WtQKV = (u16*)alloc((size_t)LL * 384 * 128 * 2);
    float* bQKV = (float*)alloc((size_t)LL * 384 * 4);
    u16* WtO   = (u16*)alloc((size_t)LL * 128 * 128 * 2);
    u16* WtF1  = (u16*)alloc((size_t)LL * 256 * 128 * 2);
    u16* WtF2  = (u16*)alloc((size_t)LL * 128 * 256 * 2);
    u16* hb    = (u16*)alloc((size_t)NN * DD * 2);
    u16* QKV   = (u16*)alloc((size_t)NN * 384 * 2);   // also reused as FFN mid (N*256)
    u16* att   = (u16*)alloc((size_t)NN * DD * 2);
    u16* h1    = (u16*)alloc((size_t)NN * DD * 2);
    u16* hmid  = (u16*)alloc((size_t)NN * DD * 2);

    // CSR build (edges identical for both layers)
    hipMemsetAsync(cnt, 0, (size_t)NN * 4, stream);
    count_kernel<<<EE / 256, 256, 0, stream>>>(dst, cnt);
    scan_kernel<<<1, 1024, 0, stream>>>(cnt, offs, cur);
    fill_kernel<<<EE / 256, 256, 0, stream>>>(src, dst, cur, srcs);

    // input + weight prep
    f2b4_kernel<<<(NN * DD / 4 + 255) / 256, 256, 0, stream>>>(h_in, hb, NN * DD / 4);
    qkvpack_kernel<<<dim3(192, LL), 256, 0, stream>>>(Wq, Wk, Wv, bq, bk, bv, WtQKV, bQKV);
    transpose_kernel<<<dim3(64, LL), 256, 0, stream>>>(Wo, WtO, 128, 128);
    transpose_kernel<<<dim3(128, LL), 256, 0, stream>>>(W1, WtF1, 128, 256);
    transpose_kernel<<<dim3(128, LL), 256, 0, stream>>>(W2, WtF2, 256, 128);

    const int MB = (NN + BM - 1) / BM;   // 782
    const u16* hcur = hb;
    for (int l = 0; l < LL; l++){
        // QKV projection (N=384)
        gemm_bf16<<<dim3(MB, 6), 256, 0, stream>>>(hcur, WtQKV + (size_t)l * 384 * 128,
                                                   bQKV + l * 384, QKV, NN, 128, 384, 0);
        // edge attention
        edge_attn_kernel<<<NN / 4, 256, 0, stream>>>(QKV, srcs, offs, att);
        // output projection + residual + LN1 (fused)
        gemm_ln<<<MB, 256, 0, stream>>>(att, WtO + (size_t)l * 128 * 128, bo + l * 128,
                                        hcur, ln1_g + l * 128, ln1_b + l * 128,
                                        h1, nullptr, NN, 128);
        // FFN up (N=256, relu)
        gemm_bf16<<<dim3(MB, 4), 256, 0, stream>>>(h1, WtF1 + (size_t)l * 256 * 128,
                                                   b1 + l * 256, QKV, NN, 128, 256, 1);
        // FFN down + residual + LN2 (fused); last layer writes fp32 d_out
        if (l == LL - 1)
            gemm_ln<<<MB, 256, 0, stream>>>(QKV, WtF2 + (size_t)l * 128 * 256, b2 + l * 128,
                                            h1, ln2_g + l * 128, ln2_b + l * 128,
                                            nullptr, outp, NN, 256);
        else
            gemm_ln<<<MB, 256, 0, stream>>>(QKV, WtF2 + (size_t)l * 128 * 256, b2 + l * 128,
                                            h1, ln2_g + l * 128, ln2_b + l * 128,
                                            hmid, nullptr, NN, 256);
        hcur = hmid;
    }
}

// Round 4
// 585.274 us; speedup vs baseline: 1.6515x; 1.1242x over previous
//
#include <hip/hip_runtime.h>

#define NN 50000
#define DD 128
#define HH 8
#define EE 1600000
#define LL 2

typedef unsigned short u16;
typedef __attribute__((ext_vector_type(8))) __bf16 bf16x8;
typedef __attribute__((ext_vector_type(4))) float f32x4;

__device__ __forceinline__ float bf2f(u16 u){
    return __uint_as_float(((unsigned int)u) << 16);
}
__device__ __forceinline__ u16 f2bf(float f){
    unsigned int x = __float_as_uint(f);
    x = x + 0x7fff + ((x >> 16) & 1);   // round-to-nearest-even
    return (u16)(x >> 16);
}

// ---------------- fp32 -> bf16 bulk convert ----------------
__global__ __launch_bounds__(256) void f2b4_kernel(const float* __restrict__ in, u16* __restrict__ out, int n4){
    int i = blockIdx.x * 256 + threadIdx.x;
    if (i < n4){
        float4 v = ((const float4*)in)[i];
        ushort4 o;
        o.x = f2bf(v.x); o.y = f2bf(v.y); o.z = f2bf(v.z); o.w = f2bf(v.w);
        ((ushort4*)out)[i] = o;
    }
}

// ---------------- CSR build ----------------
__global__ __launch_bounds__(256) void count_kernel(const int* __restrict__ dst, int* __restrict__ cnt){
    int e = blockIdx.x * 256 + threadIdx.x;
    if (e < EE) atomicAdd(&cnt[dst[e]], 1);
}

// block-wide scan over cnt (NN values), 4 values per thread per chunk.
__global__ __launch_bounds__(1024) void scan_kernel(const int* __restrict__ cnt,
                                                    int* __restrict__ offs, int* __restrict__ cur){
    __shared__ int wsum[16];
    __shared__ int carry_s;
    __shared__ int ctot_s;
    int t = threadIdx.x, lane = t & 63, w = t >> 6;
    if (t == 0){ offs[0] = 0; cur[0] = 0; carry_s = 0; }
    __syncthreads();
    const int N4 = NN / 4;   // 12500
    for (int base = 0; base < N4; base += 1024){
        int i4 = base + t;
        int4 x = (i4 < N4) ? ((const int4*)cnt)[i4] : make_int4(0, 0, 0, 0);
        int s1 = x.x, s2 = s1 + x.y, s3 = s2 + x.z, s4 = s3 + x.w;
        int v = s4;
        #pragma unroll
        for (int d = 1; d < 64; d <<= 1){ int u = __shfl_up(v, d); if (lane >= d) v += u; }
        if (lane == 63) wsum[w] = v;
        __syncthreads();
        if (t < 16){
            int sv = wsum[t];
            int iv = sv;
            #pragma unroll
            for (int d = 1; d < 16; d <<= 1){ int u = __shfl_up(iv, d); if (t >= d) iv += u; }
            wsum[t] = iv - sv;            // exclusive prefix of wave sums
            if (t == 15) ctot_s = iv;     // chunk total
        }
        __syncthreads();
        int excl = carry_s + wsum[w] + (v - s4);   // exclusive prefix for this thread's 1st elem
        if (i4 < N4){
            int o = 4 * i4;
            offs[o + 1] = excl + s1;  cur[o + 1] = excl + s1;
            offs[o + 2] = excl + s2;  cur[o + 2] = excl + s2;
            offs[o + 3] = excl + s3;  cur[o + 3] = excl + s3;
            offs[o + 4] = excl + s4;  cur[o + 4] = excl + s4;
        }
        __syncthreads();
        if (t == 0) carry_s += ctot_s;
        __syncthreads();
    }
}

// XCD-partitioned scatter: slice s (blockIdx&7) owns dst range [s*6250,(s+1)*6250).
// Scatter region per slice ~800KB -> L2-resident -> full-line write coalescing.
#define FILL_SUB 128
__global__ __launch_bounds__(256) void fill_kernel(const int* __restrict__ src, const int* __restrict__ dst,
                                                   int* __restrict__ cur, int* __restrict__ srcs){
    int slice = blockIdx.x & 7;
    int sub = blockIdx.x >> 3;          // 0..FILL_SUB-1
    int lo = slice * (NN / 8), hi = lo + (NN / 8);
    for (int e = sub * 256 + threadIdx.x; e < EE; e += FILL_SUB * 256){
        int d = dst[e];
        if (d >= lo && d < hi){
            int p = atomicAdd(&cur[d], 1);
            srcs[p] = src[e];
        }
    }
}

// ---------------- weight prep (fp32 in -> bf16 transposed out) ----------------
__global__ __launch_bounds__(256) void qkvpack_kernel(const float* __restrict__ Wq, const float* __restrict__ Wk,
                                                      const float* __restrict__ Wv, const float* __restrict__ bq,
                                                      const float* __restrict__ bk, const float* __restrict__ bv,
                                                      u16* __restrict__ Wt, float* __restrict__ bcat){
    int l = blockIdx.y;
    int idx = blockIdx.x * 256 + threadIdx.x;   // over 384*128
    if (idx < 384 * 128){
        int n = idx >> 7, k = idx & 127;
        const float* W = (n < 128) ? Wq : (n < 256) ? Wk : Wv;
        int nc = n & 127;
        Wt[(size_t)l * 384 * 128 + idx] = f2bf(W[(size_t)l * 128 * 128 + k * 128 + nc]);
        if (k == 0){
            const float* bb = (n < 128) ? bq : (n < 256) ? bk : bv;
            bcat[l * 384 + n] = bb[l * 128 + nc];
        }
    }
}

// generic transpose+convert: in fp32 [R][C] -> out bf16 [C][R], per-layer via blockIdx.y
__global__ __launch_bounds__(256) void transpose_kernel(const float* __restrict__ in, u16* __restrict__ out,
                                                        int R, int C){
    size_t mat = (size_t)blockIdx.y * R * C;
    int idx = blockIdx.x * 256 + threadIdx.x;
    if (idx < R * C){
        int r = idx / C, c = idx % C;
        out[mat + (size_t)c * R + r] = f2bf(in[mat + idx]);
    }
}

// ---------------- GEMM: out[M][N] = A[M][K] @ W[K][N] (+bias, relu) ----------------
#define BM 64
#define BN 64
#define BKK 64

__global__ __launch_bounds__(256) void gemm_bf16(const u16* __restrict__ A, const u16* __restrict__ Wt,
                                                 const float* __restrict__ bias,
                                                 u16* __restrict__ out, int M, int K, int N, int relu){
    __shared__ u16 As[BM][BKK + 8];
    __shared__ u16 Bs[BN][BKK + 8];
    int tid = threadIdx.x;
    int m0 = blockIdx.x * BM, n0 = blockIdx.y * BN;
    int lane = tid & 63, w = tid >> 6;
    int wm = w >> 1, wn = w & 1;
    int l15 = lane & 15, lk = (lane >> 4) * 8;

    f32x4 acc[2][2];
    #pragma unroll
    for (int mi = 0; mi < 2; mi++)
        #pragma unroll
        for (int ni = 0; ni < 2; ni++)
            acc[mi][ni] = (f32x4){0.f, 0.f, 0.f, 0.f};

    int sr = tid >> 3;              // 0..31
    int sc = (tid & 7) * 8;         // 0..56

    for (int k0 = 0; k0 < K; k0 += BKK){
        __syncthreads();
        #pragma unroll
        for (int p = 0; p < 2; p++){
            int row = p * 32 + sr;
            int gm = m0 + row;
            uint4 va = make_uint4(0, 0, 0, 0);
            if (gm < M) va = *(const uint4*)(A + (size_t)gm * K + k0 + sc);
            *(uint4*)(&As[row][sc]) = va;
            uint4 vb = *(const uint4*)(Wt + (size_t)(n0 + row) * K + k0 + sc);
            *(uint4*)(&Bs[row][sc]) = vb;
        }
        __syncthreads();
        #pragma unroll
        for (int ks = 0; ks < 2; ks++){
            bf16x8 a[2], b[2];
            #pragma unroll
            for (int i = 0; i < 2; i++){
                a[i] = *(const bf16x8*)(&As[wm * 32 + i * 16 + l15][ks * 32 + lk]);
                b[i] = *(const bf16x8*)(&Bs[wn * 32 + i * 16 + l15][ks * 32 + lk]);
            }
            #pragma unroll
            for (int mi = 0; mi < 2; mi++)
                #pragma unroll
                for (int ni = 0; ni < 2; ni++)
                    acc[mi][ni] = __builtin_amdgcn_mfma_f32_16x16x32_bf16(a[mi], b[ni], acc[mi][ni], 0, 0, 0);
        }
    }

    #pragma unroll
    for (int mi = 0; mi < 2; mi++)
        #pragma unroll
        for (int ni = 0; ni < 2; ni++){
            int col = n0 + wn * 32 + ni * 16 + l15;
            float bval = bias[col];
            #pragma unroll
            for (int j = 0; j < 4; j++){
                int row = m0 + wm * 32 + mi * 16 + (lane >> 4) * 4 + j;
                if (row < M){
                    float v = acc[mi][ni][j] + bval;
                    if (relu) v = fmaxf(v, 0.f);
                    out[(size_t)row * N + col] = f2bf(v);
                }
            }
        }
}

// ---------------- GEMM (N=128) + bias + residual + LayerNorm fused ----------------
__global__ __launch_bounds__(256) void gemm_ln(const u16* __restrict__ A, const u16* __restrict__ Wt,
                                               const float* __restrict__ bias, const u16* __restrict__ resid,
                                               const float* __restrict__ g, const float* __restrict__ b,
                                               u16* __restrict__ out_bf, float* __restrict__ out_f,
                                               int M, int K){
    __shared__ __align__(16) char smem[64 * 132 * 4];   // 33792 B
    u16* As = (u16*)smem;              // [64][72]
    u16* Bs = As + 64 * 72;            // [128][72]
    float* Cs = (float*)smem;          // [64][132]

    int tid = threadIdx.x;
    int m0 = blockIdx.x * 64;
    int lane = tid & 63, w = tid >> 6;
    int wm = w >> 1, wn = w & 1;
    int l15 = lane & 15, lk = (lane >> 4) * 8;

    f32x4 acc[2][4];
    #pragma unroll
    for (int mi = 0; mi < 2; mi++)
        #pragma unroll
        for (int ni = 0; ni < 4; ni++)
            acc[mi][ni] = (f32x4){0.f, 0.f, 0.f, 0.f};

    int sr = tid >> 3;              // 0..31
    int sc = (tid & 7) * 8;         // 0..56

    for (int k0 = 0; k0 < K; k0 += BKK){
        __syncthreads();
        #pragma unroll
        for (int p = 0; p < 2; p++){
            int row = p * 32 + sr;
            int gm = m0 + row;
            uint4 va = make_uint4(0, 0, 0, 0);
            if (gm < M) va = *(const uint4*)(A + (size_t)gm * K + k0 + sc);
            *(uint4*)(&As[row * 72 + sc]) = va;
        }
        #pragma unroll
        for (int p = 0; p < 4; p++){
            int row = p * 32 + sr;
            uint4 vb = *(const uint4*)(Wt + (size_t)row * K + k0 + sc);
            *(uint4*)(&Bs[row * 72 + sc]) = vb;
        }
        __syncthreads();
        #pragma unroll
        for (int ks = 0; ks < 2; ks++){
            bf16x8 a[2], bb[4];
            #pragma unroll
            for (int i = 0; i < 2; i++)
                a[i] = *(const bf16x8*)(&As[(wm * 32 + i * 16 + l15) * 72 + ks * 32 + lk]);
            #pragma unroll
            for (int i = 0; i < 4; i++)
                bb[i] = *(const bf16x8*)(&Bs[(wn * 64 + i * 16 + l15) * 72 + ks * 32 + lk]);
            #pragma unroll
            for (int mi = 0; mi < 2; mi++)
                #pragma unroll
                for (int ni = 0; ni < 4; ni++)
                    acc[mi][ni] = __builtin_amdgcn_mfma_f32_16x16x32_bf16(a[mi], bb[ni], acc[mi][ni], 0, 0, 0);
        }
    }

    __syncthreads();   // all waves done reading As/Bs; reuse as Cs
    #pragma unroll
    for (int mi = 0; mi < 2; mi++)
        #pragma unroll
        for (int ni = 0; ni < 4; ni++){
            int col = wn * 64 + ni * 16 + l15;
            float bval = bias[col];
            #pragma unroll
            for (int j = 0; j < 4; j++){
                int row = wm * 32 + mi * 16 + (lane >> 4) * 4 + j;
                Cs[row * 132 + col] = acc[mi][ni][j] + bval;
            }
        }
    __syncthreads();

    float gva = g[lane], gvb = g[lane + 64];
    float bva = b[lane], bvb = b[lane + 64];
    for (int rr = 0; rr < 16; rr++){
        int row = w * 16 + rr;
        int gr = m0 + row;
        if (gr >= M) break;
        float xa = Cs[row * 132 + lane]      + bf2f(resid[(size_t)gr * 128 + lane]);
        float xb = Cs[row * 132 + 64 + lane] + bf2f(resid[(size_t)gr * 128 + 64 + lane]);
        float s = xa + xb;
        #pragma unroll
        for (int d = 1; d < 64; d <<= 1) s += __shfl_xor(s, d);
        float mean = s * (1.f / 128.f);
        float da = xa - mean, db = xb - mean;
        float v = da * da + db * db;
        #pragma unroll
        for (int d = 1; d < 64; d <<= 1) v += __shfl_xor(v, d);
        float r = rsqrtf(v * (1.f / 128.f) + 1e-5f);
        float oa = da * r * gva + bva;
        float ob = db * r * gvb + bvb;
        if (out_f){
            out_f[(size_t)gr * 128 + lane] = oa;
            out_f[(size_t)gr * 128 + 64 + lane] = ob;
        } else {
            out_bf[(size_t)gr * 128 + lane] = f2bf(oa);
            out_bf[(size_t)gr * 128 + 64 + lane] = f2bf(ob);
        }
    }
}

// ---------------- edge attention aggregation ----------------
// QKV: [N][384] bf16 (Q|K|V). One wave per dst node.
// Lane l (<32): K dims 4l..4l+3, computes score for head l>>2. Lane l (>=32): V dims 4(l-32)..+3.
__global__ __launch_bounds__(256) void edge_attn_kernel(const u16* __restrict__ QKV,
                                                        const int* __restrict__ srcs,
                                                        const int* __restrict__ offs,
                                                        u16* __restrict__ att){
    int n = blockIdx.x * 4 + (threadIdx.x >> 6);
    if (n >= NN) return;
    int lane = threadIdx.x & 63;
    bool isV = lane >= 32;

    float q0, q1, q2, q3;
    {
        uint2 qv = *(const uint2*)(QKV + (size_t)n * 384 + 4 * (lane & 31));
        q0 = bf2f((u16)(qv.x & 0xffff)); q1 = bf2f((u16)(qv.x >> 16));
        q2 = bf2f((u16)(qv.y & 0xffff)); q3 = bf2f((u16)(qv.y >> 16));
    }
    const u16* kvbase = QKV + 128 + 4 * lane;

    float w0 = 0.f, w1 = 0.f, w2 = 0.f, w3 = 0.f, z = 0.f;

    auto proc = [&](uint2 kv){
        float a0 = bf2f((u16)(kv.x & 0xffff)), a1 = bf2f((u16)(kv.x >> 16));
        float a2 = bf2f((u16)(kv.y & 0xffff)), a3 = bf2f((u16)(kv.y >> 16));
        float p = q0 * a0 + q1 * a1 + q2 * a2 + q3 * a3;
        p += __shfl_xor(p, 1);
        p += __shfl_xor(p, 2);
        p *= 0.25f;                              // 1/sqrt(16)
        p = fminf(fmaxf(p, -5.f), 5.f);
        float sc = __expf(p);
        float scv = __shfl_xor(sc, 32);          // upper lanes receive their head's score
        float m = isV ? scv : 0.f;
        w0 += m * a0; w1 += m * a1; w2 += m * a2; w3 += m * a3;
        z += isV ? 0.f : sc;
    };

    int e0 = offs[n], e1 = offs[n + 1];
    int i = e0;
    for (; i + 7 < e1; i += 8){
        int s[8];
        #pragma unroll
        for (int u = 0; u < 8; u++) s[u] = srcs[i + u];
        uint2 kv[8];
        #pragma unroll
        for (int u = 0; u < 8; u++) kv[u] = *(const uint2*)(kvbase + (size_t)s[u] * 384);
        #pragma unroll
        for (int u = 0; u < 8; u++) proc(kv[u]);
    }
    for (; i < e1; i++){
        int s = srcs[i];
        uint2 kv = *(const uint2*)(kvbase + (size_t)s * 384);
        proc(kv);
    }

    float z2 = __shfl_xor(z, 32);                // upper lanes receive their head's z
    if (isV){
        float inv = 1.f / (z2 + 1e-6f);
        unsigned int oA = (unsigned int)f2bf(w0 * inv) | ((unsigned int)f2bf(w1 * inv) << 16);
        unsigned int oB = (unsigned int)f2bf(w2 * inv) | ((unsigned int)f2bf(w3 * inv) << 16);
        *(uint2*)(att + (size_t)n * DD + 4 * (lane - 32)) = make_uint2(oA, oB);
    }
}

// ---------------- host orchestration ----------------
extern "C" void kernel_launch(void* const* d_in, const int* in_sizes, int n_in,
                              void* d_out, int out_size, void* d_ws, size_t ws_size,
                              hipStream_t stream){
    const float* h_in = (const float*)d_in[0];
    const int* src  = (const int*)d_in[1];
    const int* dst  = (const int*)d_in[2];
    const float* Wq = (const float*)d_in[3];
    const float* bq = (const float*)d_in[4];
    const float* Wk = (const float*)d_in[5];
    const float* bk = (const float*)d_in[6];
    const float* Wv = (const float*)d_in[7];
    const float* bv = (const float*)d_in[8];
    const float* Wo = (const float*)d_in[9];
    const float* bo = (const float*)d_in[10];
    const float* W1 = (const float*)d_in[11];
    const float* b1 = (const float*)d_in[12];
    const float* W2 = (const float*)d_in[13];
    const float* b2 = (const float*)d_in[14];
    const float* ln1_g = (const float*)d_in[15];
    const float* ln1_b = (const float*)d_in[16];
    const float* ln2_g = (const float*)d_in[17];
    const float* ln2_b = (const float*)d_in[18];
    float* outp = (float*)d_out;

    char* ws = (char*)d_ws;
    auto alloc = [&](size_t bytes) -> char* {
        char* p = ws;
        ws += (bytes + 255) & ~(size_t)255;
        return p;
    };
    int* cnt   = (int*)alloc((size_t)NN * 4);
    int* offs  = (int*)alloc((size_t)(NN + 1) * 4);
    int* cur   = (int*)alloc((size_t)(NN + 1) * 4);
    int* srcs  = (int*)alloc((size_t)EE * 4);
    u16* WtQKV = (u16*)alloc((size_t)LL * 384 * 128 * 2);
    float* bQKV = (float*)alloc((size_t)LL * 384 * 4);
    u16* WtO   = (u16*)alloc((size_t)LL * 128 * 128 * 2);
    u16* WtF1  = (u16*)alloc((size_t)LL * 256 * 128 * 2);
    u16* WtF2  = (u16*)alloc((size_t)LL * 128 * 256 * 2);
    u16* hb    = (u16*)alloc((size_t)NN * DD * 2);
    u16* QKV   = (u16*)alloc((size_t)NN * 384 * 2);   // also reused as FFN mid (N*256)
    u16* att   = (u16*)alloc((size_t)NN * DD * 2);
    u16* h1    = (u16*)alloc((size_t)NN * DD * 2);
    u16* hmid  = (u16*)alloc((size_t)NN * DD * 2);

    // CSR build (edges identical for both layers)
    hipMemsetAsync(cnt, 0, (size_t)NN * 4, stream);
    count_kernel<<<EE / 256, 256, 0, stream>>>(dst, cnt);
    scan_kernel<<<1, 1024, 0, stream>>>(cnt, offs, cur);
    fill_kernel<<<8 * FILL_SUB, 256, 0, stream>>>(src, dst, cur, srcs);

    // input + weight prep
    f2b4_kernel<<<(NN * DD / 4 + 255) / 256, 256, 0, stream>>>(h_in, hb, NN * DD / 4);
    qkvpack_kernel<<<dim3(192, LL), 256, 0, stream>>>(Wq, Wk, Wv, bq, bk, bv, WtQKV, bQKV);
    transpose_kernel<<<dim3(64, LL), 256, 0, stream>>>(Wo, WtO, 128, 128);
    transpose_kernel<<<dim3(128, LL), 256, 0, stream>>>(W1, WtF1, 128, 256);
    transpose_kernel<<<dim3(128, LL), 256, 0, stream>>>(W2, WtF2, 256, 128);

    const int MB = (NN + BM - 1) / BM;   // 782
    const u16* hcur = hb;
    for (int l = 0; l < LL; l++){
        // QKV projection (N=384)
        gemm_bf16<<<dim3(MB, 6), 256, 0, stream>>>(hcur, WtQKV + (size_t)l * 384 * 128,
                                                   bQKV + l * 384, QKV, NN, 128, 384, 0);
        // edge attention
        edge_attn_kernel<<<NN / 4, 256, 0, stream>>>(QKV, srcs, offs, att);
        // output projection + residual + LN1 (fused)
        gemm_ln<<<MB, 256, 0, stream>>>(att, WtO + (size_t)l * 128 * 128, bo + l * 128,
                                        hcur, ln1_g + l * 128, ln1_b + l * 128,
                                        h1, nullptr, NN, 128);
        // FFN up (N=256, relu)
        gemm_bf16<<<dim3(MB, 4), 256, 0, stream>>>(h1, WtF1 + (size_t)l * 256 * 128,
                                                   b1 + l * 256, QKV, NN, 128, 256, 1);
        // FFN down + residual + LN2 (fused); last layer writes fp32 d_out
        if (l == LL - 1)
            gemm_ln<<<MB, 256, 0, stream>>>(QKV, WtF2 + (size_t)l * 128 * 256, b2 + l * 128,
                                            h1, ln2_g + l * 128, ln2_b + l * 128,
                                            nullptr, outp, NN, 256);
        else
            gemm_ln<<<MB, 256, 0, stream>>>(QKV, WtF2 + (size_t)l * 128 * 256, b2 + l * 128,
                                            h1, ln2_g + l * 128, ln2_b + l * 128,
                                            hmid, nullptr, NN, 256);
        hcur = hmid;
    }
}